// Round 1
// baseline (944.328 us; speedup 1.0000x reference)
//
#include <hip/hip_runtime.h>
#include <math.h>

#define N_NODES 10000
#define FT 128
#define FP 64
#define SEC 32
#define MC 7
#define C1 39            // SEC + MC columns in pass 1
#define KTILE 64
#define RB 64            // rows per block in big kernels
#define NTILES 157       // ceil(10000/64)
#define KZ 4             // k-split across blocks

// ---------------- K1: P1 = [T@Ws1 | (T|P)@Wma], Z2 = T@Ws2+bs, Zm = (T|P)@Wmb+bm
__global__ __launch_bounds__(256) void k1_lin(
    const float* __restrict__ T, const float* __restrict__ P,
    const float* __restrict__ Ws1, const float* __restrict__ Ws2,
    const float* __restrict__ bs, const float* __restrict__ Wma,
    const float* __restrict__ Wmb, const float* __restrict__ bm,
    float* __restrict__ P1, float* __restrict__ Z2, float* __restrict__ Zm) {
  __shared__ float Tl[8 * FT];
  __shared__ float Pl[8 * FP];
  int t = threadIdx.x;
  int r0 = blockIdx.x * 8;
  #pragma unroll
  for (int j = 0; j < 4; ++j) {
    int f = t + 256 * j;           // 0..1023
    int r = f >> 7, k = f & 127;
    int row = r0 + r;
    Tl[f] = (row < N_NODES) ? T[row * FT + k] : 0.f;
  }
  #pragma unroll
  for (int j = 0; j < 2; ++j) {
    int f = t + 256 * j;           // 0..511
    int r = f >> 6, k = f & 63;
    int row = r0 + r;
    Pl[f] = (row < N_NODES) ? P[row * FP + k] : 0.f;
  }
  __syncthreads();
  int r = t >> 5, c = t & 31;
  int row = r0 + r;
  const float* trow = &Tl[r * FT];
  const float* prow = &Pl[r * FP];
  float y1 = 0.f, z2 = 0.f;
  for (int k = 0; k < FT; ++k) {
    float tv = trow[k];
    y1 += tv * Ws1[k * SEC + c];
    z2 += tv * Ws2[k * SEC + c];
  }
  z2 += bs[c];
  if (row < N_NODES) {
    P1[row * C1 + c] = y1;
    Z2[row * SEC + c] = z2;
  }
  if (c < MC) {
    float ym = 0.f, zm = 0.f;
    for (int k = 0; k < FT; ++k) {
      float tv = trow[k];
      ym += tv * Wma[k * MC + c];
      zm += tv * Wmb[k * MC + c];
    }
    for (int u = 0; u < FP; ++u) {
      float pv = prow[u];
      ym += pv * Wma[(FT + u) * MC + c];
      zm += pv * Wmb[(FT + u) * MC + c];
    }
    zm += bm[c];
    if (row < N_NODES) {
      P1[row * C1 + SEC + c] = ym;
      Zm[row * MC + c] = zm;
    }
  }
}

// ---------------- K2: Spart[kz] = partial A @ P1  (39 cols)
__global__ __launch_bounds__(256) void k2_spmm(
    const float* __restrict__ A, const float* __restrict__ P1,
    float* __restrict__ Spart) {
  // Al union: A-tile 64x65 = 4160 floats  |  reduce 2 x 64 x 41 = 5248 floats
  __shared__ float Al[5248];
  __shared__ float Yl[KTILE * 40];
  int t = threadIdx.x;
  int r0 = blockIdx.x * RB;
  int kz = blockIdx.y;
  int w = t >> 6, r = t & 63;
  float acc[C1];
  #pragma unroll
  for (int c = 0; c < C1; ++c) acc[c] = 0.f;

  for (int tile = kz; tile < NTILES; tile += KZ) {
    int kt = tile * KTILE;
    __syncthreads();
    // stage A tile: 64 rows x 64 cols, float4 loads (10000 % 4 == 0)
    #pragma unroll
    for (int j = 0; j < 4; ++j) {
      int f = t + 256 * j;         // float4 index 0..1023
      int rr = f >> 4, c4 = (f & 15) * 4;
      int row = r0 + rr, k = kt + c4;
      float4 v = make_float4(0.f, 0.f, 0.f, 0.f);
      if (row < N_NODES && k < N_NODES)
        v = *(const float4*)&A[(size_t)row * N_NODES + k];
      float* d = &Al[rr * 65 + c4];
      d[0] = v.x; d[1] = v.y; d[2] = v.z; d[3] = v.w;
    }
    // stage Y tile: 64 x 39 (pad 40)
    #pragma unroll
    for (int j = 0; j < 10; ++j) {
      int s = t + 256 * j;         // 0..2559
      int kk = s / 40, cc = s - kk * 40;
      int kr = kt + kk;
      float v = 0.f;
      if (cc < C1 && kr < N_NODES) v = P1[kr * C1 + cc];
      Yl[s] = v;
    }
    __syncthreads();
    // compute: 16 k's per thread (k = 4*j + w), broadcast Y rows
    for (int j = 0; j < 16; ++j) {
      int kk = 4 * j + w;
      float a = Al[r * 65 + kk];
      const float* yrow = &Yl[kk * 40];
      #pragma unroll
      for (int c = 0; c < C1; ++c) acc[c] += a * yrow[c];
    }
  }
  // reduce 4 waves -> wave 0
  __syncthreads();
  if (w & 1) {
    float* dst = &Al[(w >> 1) * 2624 + r * 41];
    #pragma unroll
    for (int c = 0; c < C1; ++c) dst[c] = acc[c];
  }
  __syncthreads();
  if (!(w & 1)) {
    const float* src = &Al[(w >> 1) * 2624 + r * 41];
    #pragma unroll
    for (int c = 0; c < C1; ++c) acc[c] += src[c];
  }
  __syncthreads();
  if (w == 2) {
    float* dst = &Al[r * 41];
    #pragma unroll
    for (int c = 0; c < C1; ++c) dst[c] = acc[c];
  }
  __syncthreads();
  if (w == 0) {
    const float* src = &Al[r * 41];
    #pragma unroll
    for (int c = 0; c < C1; ++c) acc[c] += src[c];
    int row = r0 + r;
    if (row < N_NODES) {
      float* dst = &Spart[((size_t)kz * N_NODES + row) * C1];
      #pragma unroll
      for (int c = 0; c < C1; ++c) dst[c] = acc[c];
    }
  }
}

// ---------------- K2b: sec = relu(S1+Z2), M0 = 0.5*v2*(Sm+Zm)
__global__ __launch_bounds__(256) void k2b(
    const float* __restrict__ Spart, const float* __restrict__ Z2,
    const float* __restrict__ Zm, const float* __restrict__ v2p,
    float* __restrict__ sec, float* __restrict__ M0) {
  int g = blockIdx.x * 256 + threadIdx.x;
  if (g >= N_NODES * C1) return;
  int row = g / C1, c = g - row * C1;
  const size_t stride = (size_t)N_NODES * C1;
  float s = Spart[g] + Spart[stride + g] + Spart[2 * stride + g] + Spart[3 * stride + g];
  if (c < SEC) {
    s += Z2[row * SEC + c];
    sec[row * SEC + c] = fmaxf(s, 0.f);
  } else {
    int j = c - SEC;
    s += Zm[row * MC + j];
    M0[row * MC + j] = 0.5f * v2p[0] * s;
  }
}

// ---------------- K2c: Y2 = [sec|P]@Wm2a ; C0 = M0 + 0.5*v1*([sec|P]@Wm2b + bm2)
__global__ __launch_bounds__(256) void k2c(
    const float* __restrict__ sec, const float* __restrict__ P,
    const float* __restrict__ Wm2a, const float* __restrict__ Wm2b,
    const float* __restrict__ bm2, const float* __restrict__ v1p,
    const float* __restrict__ M0, float* __restrict__ Y2, float* __restrict__ C0) {
  int g = blockIdx.x * 256 + threadIdx.x;
  if (g >= N_NODES * MC) return;
  int row = g / MC, j = g - row * MC;
  float y = 0.f, z = 0.f;
  for (int c = 0; c < SEC; ++c) {
    float sv = sec[row * SEC + c];
    y += sv * Wm2a[c * MC + j];
    z += sv * Wm2b[c * MC + j];
  }
  for (int u = 0; u < FP; ++u) {
    float pv = P[row * FP + u];
    y += pv * Wm2a[(SEC + u) * MC + j];
    z += pv * Wm2b[(SEC + u) * MC + j];
  }
  z += bm2[j];
  Y2[g] = y;
  C0[g] = M0[g] + 0.5f * v1p[0] * z;
}

// ---------------- K3: S2part[kz] = partial A @ Y2  (7 cols)
__global__ __launch_bounds__(256) void k3_spmm(
    const float* __restrict__ A, const float* __restrict__ Y2,
    float* __restrict__ S2part) {
  __shared__ float Al[4160];       // A-tile 64x65; reduce reuses 2x64x8=1024
  __shared__ float Yl[KTILE * 8];
  int t = threadIdx.x;
  int r0 = blockIdx.x * RB;
  int kz = blockIdx.y;
  int w = t >> 6, r = t & 63;
  float acc[MC];
  #pragma unroll
  for (int c = 0; c < MC; ++c) acc[c] = 0.f;

  for (int tile = kz; tile < NTILES; tile += KZ) {
    int kt = tile * KTILE;
    __syncthreads();
    #pragma unroll
    for (int j = 0; j < 4; ++j) {
      int f = t + 256 * j;
      int rr = f >> 4, c4 = (f & 15) * 4;
      int row = r0 + rr, k = kt + c4;
      float4 v = make_float4(0.f, 0.f, 0.f, 0.f);
      if (row < N_NODES && k < N_NODES)
        v = *(const float4*)&A[(size_t)row * N_NODES + k];
      float* d = &Al[rr * 65 + c4];
      d[0] = v.x; d[1] = v.y; d[2] = v.z; d[3] = v.w;
    }
    #pragma unroll
    for (int j = 0; j < 2; ++j) {
      int s = t + 256 * j;         // 0..511
      int kk = s >> 3, cc = s & 7;
      int kr = kt + kk;
      float v = 0.f;
      if (cc < MC && kr < N_NODES) v = Y2[kr * MC + cc];
      Yl[s] = v;
    }
    __syncthreads();
    for (int j = 0; j < 16; ++j) {
      int kk = 4 * j + w;
      float a = Al[r * 65 + kk];
      const float* yrow = &Yl[kk * 8];
      #pragma unroll
      for (int c = 0; c < MC; ++c) acc[c] += a * yrow[c];
    }
  }
  __syncthreads();
  if (w & 1) {
    float* dst = &Al[(w >> 1) * 512 + r * 8];
    #pragma unroll
    for (int c = 0; c < MC; ++c) dst[c] = acc[c];
  }
  __syncthreads();
  if (!(w & 1)) {
    const float* src = &Al[(w >> 1) * 512 + r * 8];
    #pragma unroll
    for (int c = 0; c < MC; ++c) acc[c] += src[c];
  }
  __syncthreads();
  if (w == 2) {
    float* dst = &Al[r * 8];
    #pragma unroll
    for (int c = 0; c < MC; ++c) dst[c] = acc[c];
  }
  __syncthreads();
  if (w == 0) {
    const float* src = &Al[r * 8];
    #pragma unroll
    for (int c = 0; c < MC; ++c) acc[c] += src[c];
    int row = r0 + r;
    if (row < N_NODES) {
      float* dst = &S2part[((size_t)kz * N_NODES + row) * MC];
      #pragma unroll
      for (int c = 0; c < MC; ++c) dst[c] = acc[c];
    }
  }
}

// ---------------- K3b: combined = C0 + 0.5*v1*S2 ; softmax over 7
__global__ __launch_bounds__(256) void k3b(
    const float* __restrict__ S2part, const float* __restrict__ C0,
    const float* __restrict__ v1p, float* __restrict__ out) {
  int row = blockIdx.x * 256 + threadIdx.x;
  if (row >= N_NODES) return;
  float v1h = 0.5f * v1p[0];
  const size_t stride = (size_t)N_NODES * MC;
  float comb[MC];
  float mx = -1e30f;
  #pragma unroll
  for (int j = 0; j < MC; ++j) {
    int g = row * MC + j;
    float s = S2part[g] + S2part[stride + g] + S2part[2 * stride + g] + S2part[3 * stride + g];
    float cv = C0[g] + v1h * s;
    comb[j] = cv;
    mx = fmaxf(mx, cv);
  }
  float sum = 0.f;
  #pragma unroll
  for (int j = 0; j < MC; ++j) {
    comb[j] = expf(comb[j] - mx);
    sum += comb[j];
  }
  float inv = 1.f / sum;
  #pragma unroll
  for (int j = 0; j < MC; ++j) out[row * MC + j] = comb[j] * inv;
}

extern "C" void kernel_launch(void* const* d_in, const int* in_sizes, int n_in,
                              void* d_out, int out_size, void* d_ws, size_t ws_size,
                              hipStream_t stream) {
  const float* T    = (const float*)d_in[0];
  const float* A    = (const float*)d_in[1];
  const float* P    = (const float*)d_in[2];
  const float* Ws1  = (const float*)d_in[3];
  const float* Ws2  = (const float*)d_in[4];
  const float* bs   = (const float*)d_in[5];
  const float* Wm2a = (const float*)d_in[6];
  const float* Wm2b = (const float*)d_in[7];
  const float* bm2  = (const float*)d_in[8];
  const float* Wma  = (const float*)d_in[9];
  const float* Wmb  = (const float*)d_in[10];
  const float* bm   = (const float*)d_in[11];
  const float* v1   = (const float*)d_in[12];
  const float* v2   = (const float*)d_in[13];
  float* out = (float*)d_out;

  float* ws = (float*)d_ws;
  float* P1     = ws;                          // N*39
  float* Z2     = P1 + (size_t)N_NODES * C1;   // N*32
  float* Zm     = Z2 + (size_t)N_NODES * SEC;  // N*7
  float* Spart  = Zm + (size_t)N_NODES * MC;   // 4*N*39
  float* sec    = Spart + (size_t)4 * N_NODES * C1;  // N*32
  float* M0     = sec + (size_t)N_NODES * SEC; // N*7
  float* Y2     = M0 + (size_t)N_NODES * MC;   // N*7
  float* C0     = Y2 + (size_t)N_NODES * MC;   // N*7
  float* S2part = C0 + (size_t)N_NODES * MC;   // 4*N*7

  hipLaunchKernelGGL(k1_lin, dim3((N_NODES + 7) / 8), dim3(256), 0, stream,
                     T, P, Ws1, Ws2, bs, Wma, Wmb, bm, P1, Z2, Zm);
  hipLaunchKernelGGL(k2_spmm, dim3(NTILES, KZ), dim3(256), 0, stream, A, P1, Spart);
  hipLaunchKernelGGL(k2b, dim3((N_NODES * C1 + 255) / 256), dim3(256), 0, stream,
                     Spart, Z2, Zm, v2, sec, M0);
  hipLaunchKernelGGL(k2c, dim3((N_NODES * MC + 255) / 256), dim3(256), 0, stream,
                     sec, P, Wm2a, Wm2b, bm2, v1, M0, Y2, C0);
  hipLaunchKernelGGL(k3_spmm, dim3(NTILES, KZ), dim3(256), 0, stream, A, Y2, S2part);
  hipLaunchKernelGGL(k3b, dim3((N_NODES + 255) / 256), dim3(256), 0, stream,
                     S2part, C0, v1, out);
}

// Round 2
// 792.202 us; speedup vs baseline: 1.1920x; 1.1920x over previous
//
#include <hip/hip_runtime.h>
#include <stdint.h>
#include <math.h>

#define N_NODES 10000
#define NPAD 10048          // row stride (elements) for transposed bf16 Y arrays
#define KZ 8                // k-split across blocks in A-streaming kernels
#define NTILES 157          // ceil(10000/64)

using short8 = __attribute__((ext_vector_type(8))) short;
using f32x4  = __attribute__((ext_vector_type(4))) float;

__device__ __forceinline__ uint32_t fbits(float x){ union{float f;uint32_t u;} v; v.f=x; return v.u; }
__device__ __forceinline__ float    fval(uint32_t u){ union{float f;uint32_t u;} v; v.u=u; return v.f; }

// split a into bf16 hi (truncate) + bf16 lo (truncate of remainder): ~16-bit mantissa total
__device__ __forceinline__ void split1(float a, uint16_t& h, uint16_t& l){
  uint32_t ua = fbits(a);
  float lo = a - fval(ua & 0xFFFF0000u);
  h = (uint16_t)(ua >> 16);
  l = (uint16_t)(fbits(lo) >> 16);
}

// pack (x,y) -> hi-pair u32 and lo-pair u32
__device__ __forceinline__ void split2pack(float x, float y, uint32_t& hp, uint32_t& lp){
  uint32_t ux = fbits(x), uy = fbits(y);
  float lx = x - fval(ux & 0xFFFF0000u);
  float ly = y - fval(uy & 0xFFFF0000u);
  hp = (uy & 0xFFFF0000u) | (ux >> 16);
  lp = (fbits(ly) & 0xFFFF0000u) | (fbits(lx) >> 16);
}

// ---------------- K1: Y1 = [T@Ws1 | (T|P)@Wma] -> transposed bf16 hi/lo;
//                     Z2 = T@Ws2+bs (fp32), Zm = (T|P)@Wmb+bm (fp32)
__global__ __launch_bounds__(256) void k1(
    const float* __restrict__ T, const float* __restrict__ P,
    const float* __restrict__ Ws1, const float* __restrict__ Ws2,
    const float* __restrict__ bs, const float* __restrict__ Wma,
    const float* __restrict__ Wmb, const float* __restrict__ bm,
    uint16_t* __restrict__ Yth, uint16_t* __restrict__ Ytl,
    float* __restrict__ Z2, float* __restrict__ Zm) {
  __shared__ float Xl[16 * 192];               // 16 rows x (128 T | 64 P)
  __shared__ float RedY[16 * 7], RedZ[16 * 7];
  int t = threadIdx.x;
  int r0 = blockIdx.x * 16;                    // 625 blocks * 16 = 10000 exactly
  for (int s = t; s < 768; s += 256) {
    int r = s / 48, c4 = (s % 48) * 4;
    const float* src = (c4 < 128) ? &T[(size_t)(r0 + r) * 128 + c4]
                                  : &P[(size_t)(r0 + r) * 64 + (c4 - 128)];
    *(float4*)&Xl[r * 192 + c4] = *(const float4*)src;
  }
  __syncthreads();
  // part A: 32 sec cols x 16 rows (2 rows per thread)
  {
    int c = t & 31, r = t >> 5;
    float y0 = 0, z0 = 0, y1 = 0, z1 = 0;
    const float* x0 = &Xl[r * 192];
    const float* x1 = &Xl[(r + 8) * 192];
    #pragma unroll 8
    for (int k = 0; k < 128; ++k) {
      float w1 = Ws1[k * 32 + c], w2 = Ws2[k * 32 + c];
      float a0 = x0[k], a1 = x1[k];
      y0 += a0 * w1; z0 += a0 * w2;
      y1 += a1 * w1; z1 += a1 * w2;
    }
    int rowA = r0 + r, rowB = r0 + r + 8;
    float bsv = bs[c];
    Z2[rowA * 32 + c] = z0 + bsv;
    Z2[rowB * 32 + c] = z1 + bsv;
    uint16_t h, l;
    split1(y0, h, l); Yth[c * NPAD + rowA] = h; Ytl[c * NPAD + rowA] = l;
    split1(y1, h, l); Yth[c * NPAD + rowB] = h; Ytl[c * NPAD + rowB] = l;
  }
  // part B: 7 main cols x 16 rows, k split in halves across lane pairs
  int u = t & 15, r = t >> 4;
  int j = u % 7, half = u / 7;
  float ym = 0, zm = 0;
  if (u < 14) {
    int kb = half * 96;
    const float* xr = &Xl[r * 192];
    #pragma unroll 4
    for (int i = 0; i < 96; ++i) {
      int k = kb + i;
      float wa = Wma[k * 7 + j], wb = Wmb[k * 7 + j];
      float xv = xr[k];
      ym += xv * wa; zm += xv * wb;
    }
    if (half == 1) { RedY[r * 7 + j] = ym; RedZ[r * 7 + j] = zm; }
  }
  __syncthreads();
  if (u < 7) {
    ym += RedY[r * 7 + j]; zm += RedZ[r * 7 + j];
    int row = r0 + r;
    uint16_t h, l;
    split1(ym, h, l);
    Yth[(32 + j) * NPAD + row] = h; Ytl[(32 + j) * NPAD + row] = l;
    Zm[row * 7 + j] = zm + bm[j];
  }
}

// ---------------- A-streaming MFMA kernel: Sacc += A @ Y  (bf16-split, 3 MFMAs)
// Block: 256 threads = 4 waves, 64 output rows (wave w -> rows 16w..16w+15).
// k-tiles of 64, k-split KZ across blockIdx.y, fp32 atomic accumulation.
template<int NCF, int NC, int CST>
__global__ __launch_bounds__(256) void k_spmm(
    const float* __restrict__ A, const uint16_t* __restrict__ Yth,
    const uint16_t* __restrict__ Ytl, float* __restrict__ Sacc) {
  __shared__ uint16_t Ah[64 * 72];       // 64 rows x 64 k (pad 8)
  __shared__ uint16_t Al[64 * 72];
  __shared__ uint16_t Yh[NCF * 16 * 72]; // cols x 64 k (pad 8)
  __shared__ uint16_t Yl[NCF * 16 * 72];
  int t = threadIdx.x;
  int r0 = blockIdx.x * 64;
  int kz = blockIdx.y;
  int w = t >> 6, lane = t & 63;
  int m = lane & 15, q = lane >> 4;
  f32x4 acc[NCF];
  #pragma unroll
  for (int f = 0; f < NCF; ++f) acc[f] = (f32x4){0.f, 0.f, 0.f, 0.f};

  for (int tile = kz; tile < NTILES; tile += KZ) {
    int kt = tile * 64;
    __syncthreads();
    // stage A 64x64 fp32 -> bf16 hi/lo in LDS
    #pragma unroll
    for (int jj = 0; jj < 4; ++jj) {
      int fi = t + 256 * jj;                // 0..1023 float4 slots
      int rr = fi >> 4, c4 = (fi & 15) * 4;
      int row = r0 + rr, k = kt + c4;
      float4 v = make_float4(0.f, 0.f, 0.f, 0.f);
      if (row < N_NODES && k < N_NODES)
        v = *(const float4*)&A[(size_t)row * N_NODES + k];
      uint32_t h0, l0, h1, l1;
      split2pack(v.x, v.y, h0, l0);
      split2pack(v.z, v.w, h1, l1);
      uint2 hh; hh.x = h0; hh.y = h1;
      uint2 ll; ll.x = l0; ll.y = l1;
      *(uint2*)&Ah[rr * 72 + c4] = hh;
      *(uint2*)&Al[rr * 72 + c4] = ll;
    }
    // stage Yt cols x 64 k (bf16 already in global, transposed)
    for (int s = t; s < NCF * 16 * 32; s += 256) {
      int c = s >> 5, kk = s & 31;          // u32 granularity (2 k's)
      int k2i = kt + 2 * kk;
      uint32_t vh = 0, vl = 0;
      if (c < NC && k2i < N_NODES) {
        vh = *(const uint32_t*)&Yth[(size_t)c * NPAD + k2i];
        vl = *(const uint32_t*)&Ytl[(size_t)c * NPAD + k2i];
      }
      *(uint32_t*)&Yh[c * 72 + 2 * kk] = vh;
      *(uint32_t*)&Yl[c * 72 + 2 * kk] = vl;
    }
    __syncthreads();
    #pragma unroll
    for (int ks = 0; ks < 2; ++ks) {
      int ko = ks * 32 + q * 8;
      short8 ah = *(const short8*)&Ah[(16 * w + m) * 72 + ko];
      short8 al = *(const short8*)&Al[(16 * w + m) * 72 + ko];
      #pragma unroll
      for (int f = 0; f < NCF; ++f) {
        short8 yh = *(const short8*)&Yh[(16 * f + m) * 72 + ko];
        short8 yl = *(const short8*)&Yl[(16 * f + m) * 72 + ko];
        acc[f] = __builtin_amdgcn_mfma_f32_16x16x32_bf16(ah, yh, acc[f], 0, 0, 0);
        acc[f] = __builtin_amdgcn_mfma_f32_16x16x32_bf16(ah, yl, acc[f], 0, 0, 0);
        acc[f] = __builtin_amdgcn_mfma_f32_16x16x32_bf16(al, yh, acc[f], 0, 0, 0);
      }
    }
  }
  // C/D layout: col = lane&15 (+16f), row = 16w + q*4 + reg
  int rb = r0 + 16 * w + q * 4;
  #pragma unroll
  for (int f = 0; f < NCF; ++f) {
    int col = 16 * f + m;
    if (col < CST) {
      #pragma unroll
      for (int r4 = 0; r4 < 4; ++r4) {
        int row = rb + r4;
        if (row < N_NODES) atomicAdd(&Sacc[(size_t)row * CST + col], acc[f][r4]);
      }
    }
  }
}

// ---------------- K2b: sec = relu(S1+Z2), M0 = 0.5*v2*(Sm+Zm)
__global__ __launch_bounds__(256) void k2b(
    const float* __restrict__ Sacc, const float* __restrict__ Z2,
    const float* __restrict__ Zm, const float* __restrict__ v2p,
    float* __restrict__ sec, float* __restrict__ M0) {
  int g = blockIdx.x * 256 + threadIdx.x;
  if (g >= N_NODES * 40) return;
  int row = g / 40, c = g % 40;
  if (c < 32) {
    float s = Sacc[g] + Z2[row * 32 + c];
    sec[row * 32 + c] = fmaxf(s, 0.f);
  } else if (c < 39) {
    int j = c - 32;
    float s = Sacc[g] + Zm[row * 7 + j];
    M0[row * 7 + j] = 0.5f * v2p[0] * s;
  }
}

// ---------------- K2c: Y2 = [sec|P]@Wm2a -> transposed bf16 hi/lo;
//                      C0 = M0 + 0.5*v1*([sec|P]@Wm2b + bm2)
__global__ __launch_bounds__(256) void k2c(
    const float* __restrict__ sec, const float* __restrict__ P,
    const float* __restrict__ Wm2a, const float* __restrict__ Wm2b,
    const float* __restrict__ bm2, const float* __restrict__ v1p,
    const float* __restrict__ M0,
    uint16_t* __restrict__ Y2th, uint16_t* __restrict__ Y2tl,
    float* __restrict__ C0) {
  __shared__ float Xc[16 * 96];
  __shared__ float RedY[16 * 7], RedZ[16 * 7];
  int t = threadIdx.x;
  int r0 = blockIdx.x * 16;
  for (int s = t; s < 384; s += 256) {
    int r = s / 24, c4 = (s % 24) * 4;
    const float* src = (c4 < 32) ? &sec[(size_t)(r0 + r) * 32 + c4]
                                 : &P[(size_t)(r0 + r) * 64 + (c4 - 32)];
    *(float4*)&Xc[r * 96 + c4] = *(const float4*)src;
  }
  __syncthreads();
  int u = t & 15, r = t >> 4;
  int j = u % 7, half = u / 7;
  float y = 0, z = 0;
  if (u < 14) {
    int kb = half * 48;
    const float* xr = &Xc[r * 96];
    #pragma unroll 4
    for (int i = 0; i < 48; ++i) {
      int k = kb + i;
      y += xr[k] * Wm2a[k * 7 + j];
      z += xr[k] * Wm2b[k * 7 + j];
    }
    if (half == 1) { RedY[r * 7 + j] = y; RedZ[r * 7 + j] = z; }
  }
  __syncthreads();
  if (u < 7) {
    y += RedY[r * 7 + j]; z += RedZ[r * 7 + j];
    int row = r0 + r;
    uint16_t h, l;
    split1(y, h, l);
    Y2th[j * NPAD + row] = h; Y2tl[j * NPAD + row] = l;
    C0[row * 7 + j] = M0[row * 7 + j] + 0.5f * v1p[0] * (z + bm2[j]);
  }
}

// ---------------- K3b: combined = C0 + 0.5*v1*S2 ; softmax over 7
__global__ __launch_bounds__(256) void k3b(
    const float* __restrict__ S2, const float* __restrict__ C0,
    const float* __restrict__ v1p, float* __restrict__ out) {
  int row = blockIdx.x * 256 + threadIdx.x;
  if (row >= N_NODES) return;
  float v1h = 0.5f * v1p[0];
  float comb[7];
  float mx = -1e30f;
  #pragma unroll
  for (int j = 0; j < 7; ++j) {
    float cv = C0[row * 7 + j] + v1h * S2[row * 8 + j];
    comb[j] = cv; mx = fmaxf(mx, cv);
  }
  float sum = 0.f;
  #pragma unroll
  for (int j = 0; j < 7; ++j) { comb[j] = expf(comb[j] - mx); sum += comb[j]; }
  float inv = 1.f / sum;
  #pragma unroll
  for (int j = 0; j < 7; ++j) out[row * 7 + j] = comb[j] * inv;
}

extern "C" void kernel_launch(void* const* d_in, const int* in_sizes, int n_in,
                              void* d_out, int out_size, void* d_ws, size_t ws_size,
                              hipStream_t stream) {
  const float* T    = (const float*)d_in[0];
  const float* A    = (const float*)d_in[1];
  const float* P    = (const float*)d_in[2];
  const float* Ws1  = (const float*)d_in[3];
  const float* Ws2  = (const float*)d_in[4];
  const float* bs   = (const float*)d_in[5];
  const float* Wm2a = (const float*)d_in[6];
  const float* Wm2b = (const float*)d_in[7];
  const float* bm2  = (const float*)d_in[8];
  const float* Wma  = (const float*)d_in[9];
  const float* Wmb  = (const float*)d_in[10];
  const float* bm   = (const float*)d_in[11];
  const float* v1   = (const float*)d_in[12];
  const float* v2   = (const float*)d_in[13];
  float* out = (float*)d_out;

  float* ws = (float*)d_ws;
  float* Sacc = ws;                          // [10000][40]
  float* S2   = Sacc + 400000;               // [10000][8]
  float* Z2   = S2 + 80000;                  // [10000][32]
  float* Zm   = Z2 + 320000;                 // [10000][7]
  float* sec  = Zm + 70000;                  // [10000][32]
  float* M0   = sec + 320000;                // [10000][7]
  float* C0   = M0 + 70000;                  // [10000][7]
  uint16_t* Yth  = (uint16_t*)(C0 + 70000);  // [40][NPAD] bf16 hi
  uint16_t* Ytl  = Yth + 40 * NPAD;          // [40][NPAD] bf16 lo
  uint16_t* Y2th = Ytl + 40 * NPAD;          // [8][NPAD]
  uint16_t* Y2tl = Y2th + 8 * NPAD;          // [8][NPAD]

  hipMemsetAsync(Sacc, 0, (size_t)(400000 + 80000) * sizeof(float), stream);

  hipLaunchKernelGGL(k1, dim3(625), dim3(256), 0, stream,
                     T, P, Ws1, Ws2, bs, Wma, Wmb, bm, Yth, Ytl, Z2, Zm);
  hipLaunchKernelGGL((k_spmm<3, 39, 40>), dim3(NTILES, KZ), dim3(256), 0, stream,
                     A, Yth, Ytl, Sacc);
  hipLaunchKernelGGL(k2b, dim3((N_NODES * 40 + 255) / 256), dim3(256), 0, stream,
                     Sacc, Z2, Zm, v2, sec, M0);
  hipLaunchKernelGGL(k2c, dim3(625), dim3(256), 0, stream,
                     sec, P, Wm2a, Wm2b, bm2, v1, M0, Y2th, Y2tl, C0);
  hipLaunchKernelGGL((k_spmm<1, 7, 8>), dim3(NTILES, KZ), dim3(256), 0, stream,
                     A, Y2th, Y2tl, S2);
  hipLaunchKernelGGL(k3b, dim3((N_NODES + 255) / 256), dim3(256), 0, stream,
                     S2, C0, v1, out);
}